// Round 1
// baseline (1913.268 us; speedup 1.0000x reference)
//
#include <hip/hip_runtime.h>
#include <math.h>

#define D 128
#define A 5
#define TM 64
#define CSTR 68   // padded LDS stride for 64-wide combined tile (68*4B = 272B, 16B-aligned rows)

// ---------------- Kernel 1: node prompt (softmax attention over anchors) ----------------
__global__ __launch_bounds__(256) void node_prompt_kernel(
    const float* __restrict__ x,
    const float* __restrict__ attn_w, const float* __restrict__ attn_b,
    const float* __restrict__ anchor_node,
    float* __restrict__ node_px, int N)
{
    __shared__ float At[A * D];   // At[a*D+k] = attn_w[k*A+a]  (transposed)
    __shared__ float AN[A * D];   // anchor_node natural [A][D]
    __shared__ float Ab[A];
    int t = threadIdx.x;
    for (int f = t; f < A * D; f += 256) {
        At[(f % A) * D + (f / A)] = attn_w[f];
        AN[f] = anchor_node[f];
    }
    if (t < A) Ab[t] = attn_b[t];
    __syncthreads();

    int wid = blockIdx.x * 4 + (t >> 6);
    int nw  = gridDim.x * 4;
    int j = (t & 63) * 2;
    for (int n = wid; n < N; n += nw) {
        float2 xv = *(const float2*)&x[(size_t)n * D + j];
        float l[A];
        #pragma unroll
        for (int a = 0; a < A; a++) {
            float p = xv.x * At[a * D + j] + xv.y * At[a * D + j + 1];
            #pragma unroll
            for (int off = 32; off; off >>= 1) p += __shfl_xor(p, off);
            l[a] = p + Ab[a];
        }
        float m = l[0];
        #pragma unroll
        for (int a = 1; a < A; a++) m = fmaxf(m, l[a]);
        float s = 0.f;
        #pragma unroll
        for (int a = 0; a < A; a++) { l[a] = __expf(l[a] - m); s += l[a]; }
        float inv = 1.f / s;
        float2 o = xv;
        #pragma unroll
        for (int a = 0; a < A; a++) {
            float w = l[a] * inv;
            o.x += w * AN[a * D + j];
            o.y += w * AN[a * D + j + 1];
        }
        *(float2*)&node_px[(size_t)n * D + j] = o;
    }
}

// ---------------- Kernel 2: edge prompt + atomic scatter ----------------
__global__ __launch_bounds__(256) void edge_kernel(
    const float* __restrict__ x, const int* __restrict__ ei,
    const float* __restrict__ w_w, const float* __restrict__ w_b,
    const float* __restrict__ anchor_edge,
    float* __restrict__ edge_prompt, float* __restrict__ agg, int E, int N)
{
    __shared__ float Wt[A * 2 * D];   // Wt[a*256 + j] = w_w[j*A + a]
    __shared__ float AE[A * D];
    __shared__ float Wb[A];
    int t = threadIdx.x;
    for (int f = t; f < A * 2 * D; f += 256)
        Wt[(f % A) * (2 * D) + (f / A)] = w_w[f];
    for (int f = t; f < A * D; f += 256) AE[f] = anchor_edge[f];
    if (t < A) Wb[t] = w_b[t];
    __syncthreads();

    int wid = blockIdx.x * 4 + (t >> 6);
    int nw  = gridDim.x * 4;
    int j = (t & 63) * 2;
    for (int e = wid; e < E; e += nw) {
        int s = ei[e];
        int d = ei[(size_t)E + e];
        float2 xs = *(const float2*)&x[(size_t)s * D + j];
        float2 xd = *(const float2*)&x[(size_t)d * D + j];
        float l[A];
        #pragma unroll
        for (int a = 0; a < A; a++) {
            const float* Wa = &Wt[a * 2 * D];
            float p = xs.x * Wa[j] + xs.y * Wa[j + 1]
                    + xd.x * Wa[D + j] + xd.y * Wa[D + j + 1];
            #pragma unroll
            for (int off = 32; off; off >>= 1) p += __shfl_xor(p, off);
            p += Wb[a];
            l[a] = (p > 0.f) ? p : 0.01f * p;   // leaky_relu (slope 0.01)
        }
        float m = l[0];
        #pragma unroll
        for (int a = 1; a < A; a++) m = fmaxf(m, l[a]);
        float sum = 0.f;
        #pragma unroll
        for (int a = 0; a < A; a++) { l[a] = __expf(l[a] - m); sum += l[a]; }
        float inv = 1.f / sum;
        float2 ep = make_float2(0.f, 0.f);
        #pragma unroll
        for (int a = 0; a < A; a++) {
            float b = l[a] * inv;
            ep.x += b * AE[a * D + j];
            ep.y += b * AE[a * D + j + 1];
        }
        *(float2*)&edge_prompt[(size_t)e * D + j] = ep;
        atomicAdd(&agg[(size_t)s * D + j],     ep.x);
        atomicAdd(&agg[(size_t)s * D + j + 1], ep.y);
        atomicAdd(&agg[(size_t)d * D + j],     ep.x);
        atomicAdd(&agg[(size_t)d * D + j + 1], ep.y);
    }
}

// ---------------- helper: 4x4 outer-product FMA ----------------
__device__ __forceinline__ void fma4(float4& acc, const float4 cv,
                                     const float4 w0, const float4 w1,
                                     const float4 w2, const float4 w3)
{
    acc.x += cv.x * w0.x + cv.y * w1.x + cv.z * w2.x + cv.w * w3.x;
    acc.y += cv.x * w0.y + cv.y * w1.y + cv.z * w2.y + cv.w * w3.y;
    acc.z += cv.x * w0.z + cv.y * w1.z + cv.z * w2.z + cv.w * w3.z;
    acc.w += cv.x * w0.w + cv.y * w1.w + cv.z * w2.w + cv.w * w3.w;
}

// ---------------- Kernel 3a: h = relu([node_px, agg] @ cd1_w + cd1_b) ----------------
__global__ __launch_bounds__(256) void cd1_kernel(
    const float* __restrict__ node_px, const float* __restrict__ agg,
    const float* __restrict__ cd1_w, const float* __restrict__ cd1_b,
    float* __restrict__ h, int N)
{
    __shared__ float Wt[64 * D];       // 32 KB
    __shared__ float Cn[TM * CSTR];    // 17.4 KB
    int t = threadIdx.x;
    int n0 = blockIdx.x * TM;
    int cg = t & 31, ng = t >> 5;
    int c0 = cg * 4;
    float4 acc[8];
    #pragma unroll
    for (int jj = 0; jj < 8; jj++) acc[jj] = make_float4(0.f, 0.f, 0.f, 0.f);

    for (int kt = 0; kt < 4; kt++) {
        int k0 = kt * 64;
        __syncthreads();
        const float4* Wg = (const float4*)(cd1_w + (size_t)k0 * D);
        float4* Wl = (float4*)Wt;
        #pragma unroll
        for (int i = 0; i < 8; i++) Wl[i * 256 + t] = Wg[i * 256 + t];
        const float* src = (k0 < 128) ? node_px : agg;
        int koff = k0 & 127;
        #pragma unroll
        for (int i = 0; i < 4; i++) {
            int f = i * 256 + t;
            int n = f >> 4, k4 = f & 15;
            int nn = n0 + n; if (nn >= N) nn = N - 1;
            float4 v = *(const float4*)&src[(size_t)nn * D + koff + k4 * 4];
            *(float4*)&Cn[n * CSTR + k4 * 4] = v;
        }
        __syncthreads();
        #pragma unroll 4
        for (int k4 = 0; k4 < 16; k4++) {
            float4 w0 = *(float4*)&Wt[(k4 * 4 + 0) * D + c0];
            float4 w1 = *(float4*)&Wt[(k4 * 4 + 1) * D + c0];
            float4 w2 = *(float4*)&Wt[(k4 * 4 + 2) * D + c0];
            float4 w3 = *(float4*)&Wt[(k4 * 4 + 3) * D + c0];
            #pragma unroll
            for (int jj = 0; jj < 8; jj++) {
                float4 cv = *(float4*)&Cn[(ng * 8 + jj) * CSTR + k4 * 4];
                fma4(acc[jj], cv, w0, w1, w2, w3);
            }
        }
    }
    float4 b = *(const float4*)&cd1_b[c0];
    #pragma unroll
    for (int jj = 0; jj < 8; jj++) {
        int n = n0 + ng * 8 + jj;
        if (n < N) {
            float4 r;
            r.x = fmaxf(acc[jj].x + b.x, 0.f);
            r.y = fmaxf(acc[jj].y + b.y, 0.f);
            r.z = fmaxf(acc[jj].z + b.z, 0.f);
            r.w = fmaxf(acc[jj].w + b.w, 0.f);
            *(float4*)&h[(size_t)n * D + c0] = r;
        }
    }
}

// ---------------- Kernel 3b: cs = sigmoid(h @ cd2_w + cd2_b), in-place over h ----------------
__global__ __launch_bounds__(256) void cd2_kernel(
    const float* h_in, const float* __restrict__ cd2_w,
    const float* __restrict__ cd2_b, float* cs_out, int N)
{
    __shared__ float Wt[64 * D];
    __shared__ float Cn[TM * CSTR];
    int t = threadIdx.x;
    int n0 = blockIdx.x * TM;
    int cg = t & 31, ng = t >> 5;
    int c0 = cg * 4;
    float4 acc[8];
    #pragma unroll
    for (int jj = 0; jj < 8; jj++) acc[jj] = make_float4(0.f, 0.f, 0.f, 0.f);

    for (int kt = 0; kt < 2; kt++) {
        int k0 = kt * 64;
        __syncthreads();
        const float4* Wg = (const float4*)(cd2_w + (size_t)k0 * D);
        float4* Wl = (float4*)Wt;
        #pragma unroll
        for (int i = 0; i < 8; i++) Wl[i * 256 + t] = Wg[i * 256 + t];
        #pragma unroll
        for (int i = 0; i < 4; i++) {
            int f = i * 256 + t;
            int n = f >> 4, k4 = f & 15;
            int nn = n0 + n; if (nn >= N) nn = N - 1;
            float4 v = *(const float4*)&h_in[(size_t)nn * D + k0 + k4 * 4];
            *(float4*)&Cn[n * CSTR + k4 * 4] = v;
        }
        __syncthreads();
        #pragma unroll 4
        for (int k4 = 0; k4 < 16; k4++) {
            float4 w0 = *(float4*)&Wt[(k4 * 4 + 0) * D + c0];
            float4 w1 = *(float4*)&Wt[(k4 * 4 + 1) * D + c0];
            float4 w2 = *(float4*)&Wt[(k4 * 4 + 2) * D + c0];
            float4 w3 = *(float4*)&Wt[(k4 * 4 + 3) * D + c0];
            #pragma unroll
            for (int jj = 0; jj < 8; jj++) {
                float4 cv = *(float4*)&Cn[(ng * 8 + jj) * CSTR + k4 * 4];
                fma4(acc[jj], cv, w0, w1, w2, w3);
            }
        }
    }
    float4 b = *(const float4*)&cd2_b[c0];
    #pragma unroll
    for (int jj = 0; jj < 8; jj++) {
        int n = n0 + ng * 8 + jj;
        if (n < N) {
            float4 r;
            r.x = 1.f / (1.f + __expf(-(acc[jj].x + b.x)));
            r.y = 1.f / (1.f + __expf(-(acc[jj].y + b.y)));
            r.z = 1.f / (1.f + __expf(-(acc[jj].z + b.z)));
            r.w = 1.f / (1.f + __expf(-(acc[jj].w + b.w)));
            *(float4*)&cs_out[(size_t)n * D + c0] = r;
        }
    }
}

// ---------------- Kernel 3c: final = node_px + cs * ((node_px+agg) @ int_w + int_b) ----------------
// final_x written over node_px (same buffer): block-local read-before-write, safe.
__global__ __launch_bounds__(256) void final_kernel(
    const float* node_px, const float* __restrict__ agg,
    const float* __restrict__ cs, const float* __restrict__ int_w,
    const float* __restrict__ int_b, float* final_x, int N)
{
    __shared__ float Wt[64 * D];
    __shared__ float Cn[TM * CSTR];
    int t = threadIdx.x;
    int n0 = blockIdx.x * TM;
    int cg = t & 31, ng = t >> 5;
    int c0 = cg * 4;
    float4 acc[8];
    #pragma unroll
    for (int jj = 0; jj < 8; jj++) acc[jj] = make_float4(0.f, 0.f, 0.f, 0.f);

    for (int kt = 0; kt < 2; kt++) {
        int k0 = kt * 64;
        __syncthreads();
        const float4* Wg = (const float4*)(int_w + (size_t)k0 * D);
        float4* Wl = (float4*)Wt;
        #pragma unroll
        for (int i = 0; i < 8; i++) Wl[i * 256 + t] = Wg[i * 256 + t];
        #pragma unroll
        for (int i = 0; i < 4; i++) {
            int f = i * 256 + t;
            int n = f >> 4, k4 = f & 15;
            int nn = n0 + n; if (nn >= N) nn = N - 1;
            float4 a4 = *(const float4*)&node_px[(size_t)nn * D + k0 + k4 * 4];
            float4 b4 = *(const float4*)&agg[(size_t)nn * D + k0 + k4 * 4];
            float4 v = make_float4(a4.x + b4.x, a4.y + b4.y, a4.z + b4.z, a4.w + b4.w);
            *(float4*)&Cn[n * CSTR + k4 * 4] = v;
        }
        __syncthreads();
        #pragma unroll 4
        for (int k4 = 0; k4 < 16; k4++) {
            float4 w0 = *(float4*)&Wt[(k4 * 4 + 0) * D + c0];
            float4 w1 = *(float4*)&Wt[(k4 * 4 + 1) * D + c0];
            float4 w2 = *(float4*)&Wt[(k4 * 4 + 2) * D + c0];
            float4 w3 = *(float4*)&Wt[(k4 * 4 + 3) * D + c0];
            #pragma unroll
            for (int jj = 0; jj < 8; jj++) {
                float4 cv = *(float4*)&Cn[(ng * 8 + jj) * CSTR + k4 * 4];
                fma4(acc[jj], cv, w0, w1, w2, w3);
            }
        }
    }
    float4 b = *(const float4*)&int_b[c0];
    #pragma unroll
    for (int jj = 0; jj < 8; jj++) {
        int n = n0 + ng * 8 + jj;
        if (n < N) {
            float4 iv = make_float4(acc[jj].x + b.x, acc[jj].y + b.y,
                                    acc[jj].z + b.z, acc[jj].w + b.w);
            float4 c4 = *(const float4*)&cs[(size_t)n * D + c0];
            float4 np = *(const float4*)&node_px[(size_t)n * D + c0];
            float4 r;
            r.x = np.x + c4.x * iv.x;
            r.y = np.y + c4.y * iv.y;
            r.z = np.z + c4.z * iv.z;
            r.w = np.w + c4.w * iv.w;
            *(float4*)&final_x[(size_t)n * D + c0] = r;
        }
    }
}

extern "C" void kernel_launch(void* const* d_in, const int* in_sizes, int n_in,
                              void* d_out, int out_size, void* d_ws, size_t ws_size,
                              hipStream_t stream)
{
    const float* x           = (const float*)d_in[0];
    const float* anchor_node = (const float*)d_in[1];
    const float* attn_w      = (const float*)d_in[2];
    const float* attn_b      = (const float*)d_in[3];
    const float* anchor_edge = (const float*)d_in[4];
    const float* w_w         = (const float*)d_in[5];
    const float* w_b         = (const float*)d_in[6];
    const float* cd1_w       = (const float*)d_in[7];
    const float* cd1_b       = (const float*)d_in[8];
    const float* cd2_w       = (const float*)d_in[9];
    const float* cd2_b       = (const float*)d_in[10];
    const float* int_w       = (const float*)d_in[11];
    const float* int_b       = (const float*)d_in[12];
    const int*   ei          = (const int*)d_in[13];

    int N = in_sizes[0] / D;
    int E = in_sizes[13] / 2;

    float* out         = (float*)d_out;
    float* node_px     = out;                       // reuse final_x slot for node_px
    float* edge_prompt = out + (size_t)N * D;
    float* agg         = (float*)d_ws;              // N*D floats
    float* h           = agg + (size_t)N * D;       // N*D floats (h, then cs in-place)

    hipMemsetAsync(agg, 0, (size_t)N * D * sizeof(float), stream);

    node_prompt_kernel<<<512, 256, 0, stream>>>(x, attn_w, attn_b, anchor_node, node_px, N);
    edge_kernel<<<2048, 256, 0, stream>>>(x, ei, w_w, w_b, anchor_edge, edge_prompt, agg, E, N);

    int nb = (N + TM - 1) / TM;
    cd1_kernel<<<nb, 256, 0, stream>>>(node_px, agg, cd1_w, cd1_b, h, N);
    cd2_kernel<<<nb, 256, 0, stream>>>(h, cd2_w, cd2_b, h, N);
    final_kernel<<<nb, 256, 0, stream>>>(node_px, agg, h, int_w, int_b, node_px, N);
}